// Round 1
// baseline (151.567 us; speedup 1.0000x reference)
//
#include <hip/hip_runtime.h>

// Problem constants (from reference: n=4, L=8192, h=8, e=64, fp32)
#define N_      4
#define L_      8192
#define H_      8
#define E_      64
#define NH_     (N_ * H_)          // 32 (n,h) pairs
#define STRIDE_ (H_ * E_)          // 512 floats between consecutive s/l rows
#define SPLIT_  32                 // s-dim split for phase 1
#define CHUNK_  (L_ / SPLIT_)      // 256 s-rows per block
#define TS_     16                 // s-rows staged in LDS per iteration

// ws layout: W[NH_][E_][E_]  (W[nh][d][m] = sum_s k_feat[s,d]*v[s,m])
//            then ksum[NH_][E_]
#define WS_KV_FLOATS   ((size_t)NH_ * E_ * E_)
#define WS_TOTAL_FLOATS (WS_KV_FLOATS + (size_t)NH_ * E_)

__device__ __forceinline__ float featmap(float x) {
    // elu(x * 64^-0.25) + 1  ==  xs+1 (xs>0)  else exp(xs)
    float xs = x * 0.35355339059327373f;
    return xs > 0.0f ? xs + 1.0f : __expf(xs);
}

// ---------------------------------------------------------------------------
// Phase 1: KV[d][m] and ksum[d] accumulation over s, split-K with atomics.
// Grid: NH_ * SPLIT_ blocks, 256 threads.
// Thread (d4 = t>>4, m4 = t&15) owns a 4x4 (d,m) accumulator tile.
// ---------------------------------------------------------------------------
__global__ __launch_bounds__(256) void la_phase1(
    const float* __restrict__ keys, const float* __restrict__ values,
    float* __restrict__ ws)
{
    const int blk   = blockIdx.x;
    const int nh    = blk / SPLIT_;
    const int chunk = blk % SPLIT_;
    const int n = nh / H_, h = nh % H_;
    const int t   = threadIdx.x;
    const int d4  = t >> 4;     // 0..15 : d-group for compute
    const int m4  = t & 15;     // 0..15 : m-group for compute
    const int lrow = t >> 4;    // 0..15 : row within LDS tile for loads
    const int lf4  = t & 15;    // 0..15 : float4 column for loads

    __shared__ float kt[TS_][E_];
    __shared__ float vt[TS_][E_];

    float acc[4][4] = {{0.f}};
    float ks[4] = {0.f, 0.f, 0.f, 0.f};

    const size_t base = ((size_t)n * L_ * H_ + h) * E_;
    const int s0 = chunk * CHUNK_;

    for (int it = 0; it < CHUNK_ / TS_; ++it) {
        const int srow = s0 + it * TS_ + lrow;
        const size_t roff = base + (size_t)srow * STRIDE_;
        float4 k4 = *reinterpret_cast<const float4*>(keys   + roff + lf4 * 4);
        float4 v4 = *reinterpret_cast<const float4*>(values + roff + lf4 * 4);
        k4.x = featmap(k4.x); k4.y = featmap(k4.y);
        k4.z = featmap(k4.z); k4.w = featmap(k4.w);
        ks[0] += k4.x; ks[1] += k4.y; ks[2] += k4.z; ks[3] += k4.w;

        __syncthreads();   // previous tile fully consumed
        *reinterpret_cast<float4*>(&kt[lrow][lf4 * 4]) = k4;
        *reinterpret_cast<float4*>(&vt[lrow][lf4 * 4]) = v4;
        __syncthreads();   // tile visible

        #pragma unroll
        for (int s = 0; s < TS_; ++s) {
            float4 kk = *reinterpret_cast<const float4*>(&kt[s][d4 * 4]);
            float4 vv = *reinterpret_cast<const float4*>(&vt[s][m4 * 4]);
            float ka[4] = {kk.x, kk.y, kk.z, kk.w};
            float va[4] = {vv.x, vv.y, vv.z, vv.w};
            #pragma unroll
            for (int i = 0; i < 4; ++i)
                #pragma unroll
                for (int j = 0; j < 4; ++j)
                    acc[i][j] = fmaf(ka[i], va[j], acc[i][j]);
        }
    }

    // Accumulate KV partials: W[nh][d][m]
    float* W = ws + (size_t)nh * (E_ * E_);
    #pragma unroll
    for (int i = 0; i < 4; ++i)
        #pragma unroll
        for (int j = 0; j < 4; ++j)
            atomicAdd(&W[(d4 * 4 + i) * E_ + (m4 * 4 + j)], acc[i][j]);

    // ksum: per-thread partials -> LDS -> 64-thread column sums -> atomic
    __syncthreads();
    *reinterpret_cast<float4*>(&kt[lrow][lf4 * 4]) =
        make_float4(ks[0], ks[1], ks[2], ks[3]);
    __syncthreads();
    if (t < E_) {
        float s = 0.f;
        #pragma unroll
        for (int r = 0; r < TS_; ++r) s += kt[r][t];
        atomicAdd(&ws[WS_KV_FLOATS + (size_t)nh * E_ + t], s);
    }
}

// ---------------------------------------------------------------------------
// Phase 2: out[l][m] = z * sum_d qf[d] * W[d][m].
// Grid: NH_ * 64 blocks, 256 threads (4 waves). Each wave: 32 rows.
// lane = m for output; KV column W[:, lane] held in 64 VGPRs.
// ---------------------------------------------------------------------------
__global__ __launch_bounds__(256) void la_phase2(
    const float* __restrict__ queries, const float* __restrict__ ws,
    float* __restrict__ out)
{
    const int blk  = blockIdx.x;
    const int nh   = blk >> 6;        // 64 blocks per (n,h)
    const int tile = blk & 63;
    const int n = nh / H_, h = nh % H_;
    const int t = threadIdx.x;
    const int w = t >> 6, lane = t & 63;

    const float* W = ws + (size_t)nh * (E_ * E_);
    float kv[E_];
    #pragma unroll
    for (int d = 0; d < E_; ++d) kv[d] = W[d * E_ + lane];
    const float ksum_l = ws[WS_KV_FLOATS + (size_t)nh * E_ + lane];

    __shared__ float qbuf[4][E_];

    const size_t base = ((size_t)n * L_ * H_ + h) * E_;
    const int row0 = tile * 128 + w * 32;

    for (int r = 0; r < 32; ++r) {
        const int l = row0 + r;
        const size_t off = base + (size_t)l * STRIDE_ + lane;
        const float qf = featmap(queries[off]);

        // z = 1 / (sum_d qf[d]*ksum[d] + eps): butterfly reduce over 64 lanes
        float zp = qf * ksum_l;
        #pragma unroll
        for (int sh = 32; sh >= 1; sh >>= 1) zp += __shfl_xor(zp, sh);
        const float z = 1.0f / (zp + 1e-6f);

        // broadcast qf via wave-synchronous LDS (uniform-address reads)
        qbuf[w][lane] = qf;
        __builtin_amdgcn_wave_barrier();

        float acc = 0.f;
        #pragma unroll
        for (int d0 = 0; d0 < E_; d0 += 4) {
            float4 q4 = *reinterpret_cast<const float4*>(&qbuf[w][d0]);
            acc = fmaf(q4.x, kv[d0 + 0], acc);
            acc = fmaf(q4.y, kv[d0 + 1], acc);
            acc = fmaf(q4.z, kv[d0 + 2], acc);
            acc = fmaf(q4.w, kv[d0 + 3], acc);
        }
        __builtin_amdgcn_wave_barrier();  // keep next iter's qbuf write below reads

        out[off] = acc * z;
    }
}

extern "C" void kernel_launch(void* const* d_in, const int* in_sizes, int n_in,
                              void* d_out, int out_size, void* d_ws, size_t ws_size,
                              hipStream_t stream) {
    (void)in_sizes; (void)n_in; (void)out_size; (void)ws_size;
    const float* q = (const float*)d_in[0];
    const float* k = (const float*)d_in[1];
    const float* v = (const float*)d_in[2];
    float* outp = (float*)d_out;
    float* ws   = (float*)d_ws;

    hipMemsetAsync(d_ws, 0, WS_TOTAL_FLOATS * sizeof(float), stream);
    la_phase1<<<NH_ * SPLIT_, 256, 0, stream>>>(k, v, ws);
    la_phase2<<<NH_ * 64, 256, 0, stream>>>(q, ws, outp);
}